// Round 12
// baseline (188.539 us; speedup 1.0000x reference)
//
#include <hip/hip_runtime.h>
#include <hip/hip_bf16.h>

typedef __attribute__((ext_vector_type(8))) short short8;
typedef __attribute__((ext_vector_type(4))) float f32x4;

#define MFMA16(a,b,c) __builtin_amdgcn_mfma_f32_16x16x32_bf16((a),(b),(c),0,0,0)

static __device__ __forceinline__ unsigned int f2bf(float f){
    unsigned int u = __float_as_uint(f);
    u += 0x7FFFu + ((u >> 16) & 1u);
    return u >> 16;
}

static __device__ __forceinline__ float bf2f(unsigned short s){
    return __uint_as_float(((unsigned int)s) << 16);
}

static __device__ __forceinline__ short8 pack8(float4 a, float4 b){
    short8 r;
    r[0]=(short)f2bf(a.x); r[1]=(short)f2bf(a.y);
    r[2]=(short)f2bf(a.z); r[3]=(short)f2bf(a.w);
    r[4]=(short)f2bf(b.x); r[5]=(short)f2bf(b.y);
    r[6]=(short)f2bf(b.z); r[7]=(short)f2bf(b.w);
    return r;
}

// ---- mask dtype sniffer: int32 bools are all in {0,1}; byte-bools packed
// into int words set bytes 1..3 somewhere in the first 4096 words.
__global__ void detect_mask_k(const int* __restrict__ m, int* __restrict__ flag){
    __shared__ int any_hi;
    if (threadIdx.x == 0) any_hi = 0;
    __syncthreads();
    int acc = 0;
    #pragma unroll
    for (int it = 0; it < 16; ++it)
        acc |= m[it*256 + threadIdx.x];
    if (acc & 0xFFFFFF00) atomicOr(&any_hi, 1);
    __syncthreads();
    if (threadIdx.x == 0) *flag = any_hi;   // 1 = byte layout, 0 = int32 layout
}

// ---- bias pre-transpose: [b][q][k][h] f32 -> [b][h][q][k] bf16, mask folded
// (masked -> -1e30, col 0 force-unmasked). One block per (b,q) row.
__global__ __launch_bounds__(256) void bias_prep_k(
    const float* __restrict__ bias, const unsigned int* __restrict__ mask,
    const int* __restrict__ mflag, unsigned short* __restrict__ bbt)
{
    __shared__ unsigned short tl[8][1032];   // [h][k] bf16, padded
    __shared__ unsigned int mbits[32];       // 1024-bit mask row
    const int tid  = threadIdx.x;
    const int row  = blockIdx.x;             // b*1024 + q
    const int b    = row >> 10, q = row & 1023;
    const int lane = tid & 63, wv = tid >> 6;

    if (*mflag == 0){
        // int32 bool layout: 1024 words/row; ballot 64 lanes -> u64
        #pragma unroll
        for (int i = 0; i < 4; ++i){
            unsigned int v = mask[(size_t)row*1024 + i*256 + tid];
            unsigned long long bal = __ballot(v != 0u);
            if (lane == 0)
                *(unsigned long long*)&mbits[(i*256 + wv*64) >> 5] = bal;
        }
    } else {
        // byte bool layout: 256 u32 words/row (4 bools each)
        unsigned int v = mask[(size_t)row*256 + tid];
        unsigned int nib = (v | (v>>7) | (v>>14) | (v>>21)) & 0xFu;
        unsigned int x = nib << ((lane & 7)*4);
        x |= (unsigned int)__shfl_xor((int)x, 1);
        x |= (unsigned int)__shfl_xor((int)x, 2);
        x |= (unsigned int)__shfl_xor((int)x, 4);
        if ((lane & 7) == 0) mbits[tid >> 3] = x;
    }
    __syncthreads();

    // read 32KB bias row (8 x float4/thread), fold mask, transpose h<->k in LDS
    const int h0 = (tid & 1) * 4;
    #pragma unroll
    for (int i = 0; i < 8; ++i){
        float4 v = *(const float4*)(bias + (size_t)row*8192 + i*1024 + tid*4);
        int k = i*128 + (tid >> 1);
        bool msk = (((mbits[k>>5] >> (k&31)) & 1u) != 0u) && (k != 0);
        if (msk){ v.x = -1e30f; v.y = -1e30f; v.z = -1e30f; v.w = -1e30f; }
        tl[h0  ][k] = (unsigned short)f2bf(v.x);
        tl[h0+1][k] = (unsigned short)f2bf(v.y);
        tl[h0+2][k] = (unsigned short)f2bf(v.z);
        tl[h0+3][k] = (unsigned short)f2bf(v.w);
    }
    __syncthreads();

    // write 8 coalesced 2KB rows: bbt[(b*8+h)*1024 + q][k]
    #pragma unroll
    for (int h = 0; h < 8; ++h){
        uint2 d = *(const uint2*)&tl[h][tid*4];
        *(uint2*)(bbt + ((size_t)(b*8+h)*1024 + q)*1024 + tid*4) = d;
    }
}

// ---------------- QKV projection (3-way split grid) ----------------
__global__ __launch_bounds__(256) void qkv_proj_k(
    const float* __restrict__ nd,
    const float* __restrict__ Wqp, const float* __restrict__ bqp,
    const float* __restrict__ Wkp, const float* __restrict__ bkp,
    const float* __restrict__ Wvp, const float* __restrict__ bvp,
    unsigned short* __restrict__ qout, unsigned short* __restrict__ kout,
    unsigned short* __restrict__ vtout)
{
    __shared__ __align__(16) unsigned short xl[64*264];
    const int tid  = threadIdx.x;
    const int bi   = blockIdx.x;          // 384 = 3 kinds x 128 tiles
    const int kind = bi >> 7;
    const int R0   = (bi & 127) * 64;
    const int b    = R0 >> 10;
    const int n0   = R0 & 1023;

    #pragma unroll
    for (int it = 0; it < 16; ++it){
        int f4 = it*256 + tid;
        int r = f4 >> 6, c4 = f4 & 63;
        float4 v = *(const float4*)(nd + (size_t)(R0+r)*256 + c4*4);
        unsigned int lo = f2bf(v.x) | (f2bf(v.y) << 16);
        unsigned int hi = f2bf(v.z) | (f2bf(v.w) << 16);
        *(uint2*)&xl[r*264 + c4*4] = make_uint2(lo, hi);
    }
    __syncthreads();

    const int lane = tid & 63;
    const int w  = tid >> 6;
    const int ln = lane & 15;
    const int g  = lane >> 4;
    const int ow = w * 64;

    f32x4 acc[4][4];
    #pragma unroll
    for (int a=0;a<4;++a){
        #pragma unroll
        for (int c=0;c<4;++c) acc[a][c] = (f32x4){0.f,0.f,0.f,0.f};
    }

    if (kind < 2){
        const float* W  = kind ? Wkp : Wqp;
        const float* bb = kind ? bkp : bqp;
        unsigned short* op = kind ? kout : qout;
        const float scl = kind ? 1.0f : 0.17677669529663687f;
        for (int kk = 0; kk < 8; ++kk){
            short8 wf[4], xf[4];
            #pragma unroll
            for (int ot=0; ot<4; ++ot){
                const float* wp = W + (size_t)(ow + ot*16 + ln)*256 + kk*32 + g*8;
                wf[ot] = pack8(*(const float4*)wp, *(const float4*)(wp+4));
            }
            #pragma unroll
            for (int nt=0; nt<4; ++nt)
                xf[nt] = *(const short8*)&xl[(nt*16+ln)*264 + kk*32 + g*8];
            #pragma unroll
            for (int ot=0; ot<4; ++ot){
                #pragma unroll
                for (int nt=0; nt<4; ++nt)
                    acc[ot][nt] = MFMA16(wf[ot], xf[nt], acc[ot][nt]);
            }
        }
        #pragma unroll
        for (int ot=0; ot<4; ++ot){
            int o0 = ow + ot*16 + g*4;
            int h = o0 >> 5, d0 = o0 & 31;
            float4 b4 = *(const float4*)(bb + o0);
            #pragma unroll
            for (int nt=0; nt<4; ++nt){
                int n = n0 + nt*16 + ln;
                unsigned int lo = f2bf((acc[ot][nt][0]+b4.x)*scl) | (f2bf((acc[ot][nt][1]+b4.y)*scl)<<16);
                unsigned int hi = f2bf((acc[ot][nt][2]+b4.z)*scl) | (f2bf((acc[ot][nt][3]+b4.w)*scl)<<16);
                *(uint2*)(op + ((size_t)(b*8+h)*1024 + n)*32 + d0) = make_uint2(lo,hi);
            }
        }
    } else {
        for (int kk = 0; kk < 8; ++kk){
            short8 wf[4], xf[4];
            #pragma unroll
            for (int ot=0; ot<4; ++ot){
                const float* wp = Wvp + (size_t)(ow + ot*16 + ln)*256 + kk*32 + g*8;
                wf[ot] = pack8(*(const float4*)wp, *(const float4*)(wp+4));
            }
            #pragma unroll
            for (int nt=0; nt<4; ++nt)
                xf[nt] = *(const short8*)&xl[(nt*16+ln)*264 + kk*32 + g*8];
            #pragma unroll
            for (int nt=0; nt<4; ++nt){
                #pragma unroll
                for (int ot=0; ot<4; ++ot)
                    acc[nt][ot] = MFMA16(xf[nt], wf[ot], acc[nt][ot]);
            }
        }
        #pragma unroll
        for (int nt=0; nt<4; ++nt){
            int nb = n0 + nt*16 + g*4;
            #pragma unroll
            for (int ot=0; ot<4; ++ot){
                int o = ow + ot*16 + ln;
                int h = o >> 5, d = o & 31;
                float bvv = bvp[o];
                unsigned int lo = f2bf(acc[nt][ot][0]+bvv) | (f2bf(acc[nt][ot][1]+bvv)<<16);
                unsigned int hi = f2bf(acc[nt][ot][2]+bvv) | (f2bf(acc[nt][ot][3]+bvv)<<16);
                *(uint2*)(vtout + ((size_t)(b*8+h)*32 + d)*1024 + nb) = make_uint2(lo,hi);
            }
        }
    }
}

// ---------------- Fused attention v2: zero LDS, zero barriers ----------------
// Grid 1024 = b(8) x qt(64) x hg(2); 4 waves/block, 1 head/wave, free-running.
// kperm'd K rows make lane's S^T keys = 8g..8g+7 (r9/r10-verified), matching
// one contiguous short8 from the pre-transposed bf16 bias (mask pre-folded).
// Fixed-max softmax. 2-deep register pipeline; compiler-counted vmcnt only.
__global__ __launch_bounds__(256, 4) void attn2_k(
    const unsigned short* __restrict__ qbuf, const unsigned short* __restrict__ kbuf,
    const unsigned short* __restrict__ vtbuf, const unsigned short* __restrict__ bbt,
    unsigned short* __restrict__ ab)
{
    const int tid  = threadIdx.x;
    const int bi   = blockIdx.x;
    const int hg   = bi & 1;
    const int qt   = (bi >> 1) & 63;
    const int b    = bi >> 7;
    const int q0   = qt * 16;
    const int lane = tid & 63;
    const int w    = tid >> 6;
    const int ln   = lane & 15;
    const int g    = lane >> 4;
    const int h    = hg*4 + w;

    const short8 qf = *(const short8*)(qbuf + ((size_t)(b*8+h)*1024 + q0 + ln)*32 + g*8);
    const int kperm = ((ln >> 2) << 3) + (ln & 3);
    const unsigned short* kp = kbuf  + ((size_t)(b*8+h)*1024 + kperm)*32 + g*8;
    const unsigned short* vp = vtbuf + ((size_t)(b*8+h)*32 + ln)*1024 + g*8;
    const unsigned short* bp = bbt   + ((size_t)(b*8+h)*1024 + q0 + ln)*1024 + g*8;

    f32x4 acc0 = (f32x4){0.f,0.f,0.f,0.f};
    f32x4 acc1 = (f32x4){0.f,0.f,0.f,0.f};
    float lsum = 0.f;
    const f32x4 z4 = {0.f,0.f,0.f,0.f};

    short8 k0A,k1A,v0A,v1A,bbA, k0B,k1B,v0B,v1B,bbB;

#define LOADC(S, cc) do { int c_ = (cc); \
    k0##S = *(const short8*)(kp + c_*1024); \
    k1##S = *(const short8*)(kp + c_*1024 + 128); \
    v0##S = *(const short8*)(vp + c_*32); \
    v1##S = *(const short8*)(vp + c_*32 + 16*1024); \
    bb##S = *(const short8*)(bp + c_*32); } while(0)

#define COMPC(S) do { \
    f32x4 s0 = MFMA16(k0##S, qf, z4); \
    f32x4 s1 = MFMA16(k1##S, qf, z4); \
    float e0 = __expf(s0[0] + bf2f((unsigned short)bb##S[0])); \
    float e1 = __expf(s0[1] + bf2f((unsigned short)bb##S[1])); \
    float e2 = __expf(s0[2] + bf2f((unsigned short)bb##S[2])); \
    float e3 = __expf(s0[3] + bf2f((unsigned short)bb##S[3])); \
    float e4 = __expf(s1[0] + bf2f((unsigned short)bb##S[4])); \
    float e5 = __expf(s1[1] + bf2f((unsigned short)bb##S[5])); \
    float e6 = __expf(s1[2] + bf2f((unsigned short)bb##S[6])); \
    float e7 = __expf(s1[3] + bf2f((unsigned short)bb##S[7])); \
    lsum += ((e0+e1)+(e2+e3)) + ((e4+e5)+(e6+e7)); \
    int4 pw_ = make_int4( \
        (int)(f2bf(e0) | (f2bf(e1)<<16)), (int)(f2bf(e2) | (f2bf(e3)<<16)), \
        (int)(f2bf(e4) | (f2bf(e5)<<16)), (int)(f2bf(e6) | (f2bf(e7)<<16))); \
    short8 pf_ = *(short8*)&pw_; \
    acc0 = MFMA16(v0##S, pf_, acc0); \
    acc1 = MFMA16(v1##S, pf_, acc1); } while(0)

    LOADC(A, 0);
    #pragma unroll 1
    for (int c = 0; c < 32; c += 2){
        LOADC(B, c + 1);            // in flight during COMPC(A)
        COMPC(A);
        if (c + 2 < 32) LOADC(A, c + 2);
        COMPC(B);
    }

    float ps = lsum;
    ps += __shfl_xor(ps, 16);
    ps += __shfl_xor(ps, 32);
    float inv = 1.0f / ps;
    {
        size_t orow = ((size_t)(b*1024 + q0 + ln))*256 + h*32;
        unsigned int lo0 = f2bf(acc0[0]*inv) | (f2bf(acc0[1]*inv)<<16);
        unsigned int hi0 = f2bf(acc0[2]*inv) | (f2bf(acc0[3]*inv)<<16);
        *(uint2*)(ab + orow + g*4) = make_uint2(lo0,hi0);
        unsigned int lo1 = f2bf(acc1[0]*inv) | (f2bf(acc1[1]*inv)<<16);
        unsigned int hi1 = f2bf(acc1[2]*inv) | (f2bf(acc1[3]*inv)<<16);
        *(uint2*)(ab + orow + 16 + g*4) = make_uint2(lo1,hi1);
    }
#undef LOADC
#undef COMPC
}

// ---------------- Output projection (32-row tiles) ----------------
__global__ __launch_bounds__(256) void oproj_k(
    const unsigned short* __restrict__ ab, const float* __restrict__ Wop,
    const float* __restrict__ bop, float* __restrict__ out)
{
    __shared__ __align__(16) unsigned short al[32*264];
    const int tid = threadIdx.x;
    const int R0 = blockIdx.x * 32;   // 256 blocks
    #pragma unroll
    for (int it=0; it<4; ++it){
        int f8 = it*256 + tid;
        int r = f8 >> 5, c8 = f8 & 31;
        *(short8*)&al[r*264 + c8*8] = *(const short8*)(ab + (size_t)(R0+r)*256 + c8*8);
    }
    __syncthreads();
    const int lane = tid & 63;
    const int w = tid >> 6, ln = lane & 15, g = lane >> 4;
    const int ow = w*64;
    f32x4 acc[4][2];
    #pragma unroll
    for (int a=0;a<4;++a){ acc[a][0]=(f32x4){0.f,0.f,0.f,0.f}; acc[a][1]=(f32x4){0.f,0.f,0.f,0.f}; }
    for (int kk=0;kk<8;++kk){
        short8 wf[4], xf[2];
        #pragma unroll
        for (int ot=0;ot<4;++ot){
            const float* wp = Wop + (size_t)(ow+ot*16+ln)*256 + kk*32 + g*8;
            wf[ot] = pack8(*(const float4*)wp, *(const float4*)(wp+4));
        }
        #pragma unroll
        for (int nt=0;nt<2;++nt)
            xf[nt] = *(const short8*)&al[(nt*16+ln)*264 + kk*32 + g*8];
        #pragma unroll
        for (int ot=0;ot<4;++ot){
            #pragma unroll
            for (int nt=0;nt<2;++nt)
                acc[ot][nt] = MFMA16(wf[ot], xf[nt], acc[ot][nt]);
        }
    }
    #pragma unroll
    for (int ot=0;ot<4;++ot){
        int o0 = ow + ot*16 + g*4;
        float4 b4 = *(const float4*)(bop + o0);
        #pragma unroll
        for (int nt=0;nt<2;++nt){
            int n = R0 + nt*16 + ln;
            float4 res;
            res.x = acc[ot][nt][0] + b4.x;
            res.y = acc[ot][nt][1] + b4.y;
            res.z = acc[ot][nt][2] + b4.z;
            res.w = acc[ot][nt][3] + b4.w;
            *(float4*)(out + (size_t)n*256 + o0) = res;
        }
    }
}

extern "C" void kernel_launch(void* const* d_in, const int* in_sizes, int n_in,
                              void* d_out, int out_size, void* d_ws, size_t ws_size,
                              hipStream_t stream)
{
    (void)in_sizes; (void)n_in; (void)out_size; (void)ws_size;
    const float* nd   = (const float*)d_in[0];
    // d_in[1] = N scalar (compile-time 1024 here)
    const float* bias = (const float*)d_in[2];
    const int* mask   = (const int*)d_in[3];
    const float* Wq = (const float*)d_in[4];
    const float* bq = (const float*)d_in[5];
    const float* Wk = (const float*)d_in[6];
    const float* bk = (const float*)d_in[7];
    const float* Wv = (const float*)d_in[8];
    const float* bv = (const float*)d_in[9];
    const float* Wo = (const float*)d_in[10];
    const float* bo = (const float*)d_in[11];
    float* out = (float*)d_out;

    const size_t ELEMS = (size_t)8*8*1024*32;       // 2M bf16 per buffer
    unsigned short* qb  = (unsigned short*)d_ws;
    unsigned short* kb  = qb  + ELEMS;
    unsigned short* vtb = kb  + ELEMS;
    unsigned short* ab  = vtb + ELEMS;
    unsigned short* bbt = ab  + ELEMS;              // 67.1M bf16 = 134 MB (ws >= 1 GiB per fill evidence)
    int* mflag          = (int*)(bbt + (size_t)8*8*1024*1024);

    detect_mask_k<<<1, 256, 0, stream>>>(mask, mflag);
    qkv_proj_k<<<384, 256, 0, stream>>>(nd, Wq, bq, Wk, bk, Wv, bv, qb, kb, vtb);
    bias_prep_k<<<8192, 256, 0, stream>>>(bias, (const unsigned int*)mask, mflag, bbt);
    attn2_k<<<1024, 256, 0, stream>>>(qb, kb, vtb, bbt, ab);
    oproj_k<<<256, 256, 0, stream>>>(ab, Wo, bo, out);
}